// Round 3
// baseline (377.642 us; speedup 1.0000x reference)
//
#include <hip/hip_runtime.h>

#define N_ELEM 4096
#define BLOCK 512
#define PER 8              // N_ELEM / BLOCK
#define NWAVE (BLOCK / 64)
#define NITER 40
#define CAPACITY 600.0f
#define DAMPING 1e-3f

// Raw v_rcp_f32 (~1 ulp); Newton path-following is self-correcting, tol 2e-2.
__device__ __forceinline__ float raw_rcp(float a) { return __builtin_amdgcn_rcpf(a); }

__device__ __forceinline__ float bcast_first(float v) {
    return __uint_as_float(__builtin_amdgcn_readfirstlane(__float_as_uint(v)));
}

// Fused 2-value block sum-reduction. ONE barrier; caller provides the parity
// buffer (2*NWAVE floats). Result broadcast to all threads.
__device__ __forceinline__ void block_reduce2(float& a, float& b, float* buf) {
    #pragma unroll
    for (int off = 32; off > 0; off >>= 1) {
        a += __shfl_xor(a, off, 64);
        b += __shfl_xor(b, off, 64);
    }
    const int wave = threadIdx.x >> 6;
    if ((threadIdx.x & 63) == 0) { buf[2 * wave] = a; buf[2 * wave + 1] = b; }
    __syncthreads();
    float a0 = 0.0f, b0 = 0.0f;
    #pragma unroll
    for (int i = 0; i < NWAVE; ++i) { a0 += buf[2 * i]; b0 += buf[2 * i + 1]; }
    a = a0; b = b0;
}

// Block max-reduction, ONE barrier, parity buffer (NWAVE floats), broadcast.
__device__ __forceinline__ float block_reduce_max(float v, float* buf) {
    #pragma unroll
    for (int off = 32; off > 0; off >>= 1) v = fmaxf(v, __shfl_xor(v, off, 64));
    const int wave = threadIdx.x >> 6;
    if ((threadIdx.x & 63) == 0) buf[wave] = v;
    __syncthreads();
    float m = buf[0];
    #pragma unroll
    for (int i = 1; i < NWAVE; ++i) m = fmaxf(m, buf[i]);
    return m;
}

// launch_bounds(512,5): >=5 waves/SIMD => reg cap 102. State is 48 floats +
// temps (~85) so everything stays in arch VGPRs - no AGPR ping-pong (round-2
// lesson: 96 state floats @256thr compiled to 84 VGPR + ~85 AGPR).
__global__ __launch_bounds__(BLOCK, 5) void ipm_knapsack_kernel(
        const float* __restrict__ costs,
        const float* __restrict__ weights,
        float* __restrict__ out) {
    // Parity-double-buffered reduction scratch: no tail barrier needed.
    // Safety: a slot's readers are >=2 barriers ahead of its next writer.
    __shared__ float ldsA[2][2 * NWAVE];
    __shared__ float ldsM[2][NWAVE];
    const int row = blockIdx.x;
    const int t   = threadIdx.x;

    float c[PER], w[PER], x[PER], g[PER], wih[PER], tinv[PER];

    const float4* c4 = reinterpret_cast<const float4*>(costs + (size_t)row * N_ELEM);
    const float4* w4 = reinterpret_cast<const float4*>(weights);
    #pragma unroll
    for (int k = 0; k < PER / 4; ++k) {
        float4 cc = c4[t + BLOCK * k];
        float4 ww = w4[t + BLOCK * k];
        c[4*k+0] = -cc.x; c[4*k+1] = -cc.y; c[4*k+2] = -cc.z; c[4*k+3] = -cc.w;
        w[4*k+0] =  ww.x; w[4*k+1] =  ww.y; w[4*k+2] =  ww.z; w[4*k+3] =  ww.w;
    }

    // x0 = capacity / sum(weights). Init reduce uses ldsA[0]; iteration `it`
    // uses ldsA[(it+1)&1], ldsM[it&1] -> first reuse of ldsA[0] is it=1,
    // separated from init readers by it=0's two barriers.
    float ws = 0.0f, zz = 0.0f;
    #pragma unroll
    for (int k = 0; k < PER; ++k) ws += w[k];
    block_reduce2(ws, zz, ldsA[0]);
    const float x0 = CAPACITY / ws;
    #pragma unroll
    for (int k = 0; k < PER; ++k) x[k] = x0;
    float lam = 0.0f;
    // Newton identity: sum(w*dx) = -F2  =>  F2 <- (1-alpha)*F2 analytically.
    float f2 = fmaf(x0, ws, -CAPACITY);

    for (int it = 0; it <= NITER; ++it) {
        const float mu   = (it < 10) ? __uint_as_float((unsigned)(127 - it) << 23) : DAMPING;
        const float m2mu = -2.0f * mu;

        // ---- Phase A: u=x(1-x); one rcp gives 1/u and 1/H = u^3/(u*d) ----
        float s1 = 0.0f, s2 = 0.0f;
        #pragma unroll
        for (int k = 0; k < PER; ++k) {
            const float xk = x[k], wk = w[k];
            const float p   = 1.0f - xk;
            const float u   = xk * p;
            const float d   = fmaf(m2mu, u, mu);          // mu*(1-2u) > 0
            const float r   = raw_rcp(u * d);
            const float ti  = r * d;                      // 1/u
            const float q   = xk - p;                     // 2x-1
            const float f1  = fmaf(mu * ti, q, fmaf(lam, wk, c[k]));
            const float u2  = u * u;
            const float iH  = (u2 * u) * r;               // 1/H
            const float gk  = f1 * iH;
            const float wi  = wk * iH;
            s1 = fmaf(wk, gk, s1);
            s2 = fmaf(wk, wi, s2);
            g[k] = gk; wih[k] = wi; tinv[k] = ti;
        }
        block_reduce2(s1, s2, ldsA[(it + 1) & 1]);
        const float dlam = bcast_first((f2 - s1) * raw_rcp(s2));

        if (it == NITER) {
            float4* o4 = reinterpret_cast<float4*>(out + (size_t)row * N_ELEM);
            #pragma unroll
            for (int k = 0; k < PER / 4; ++k) {
                float4 v;
                v.x = x[4*k+0] - fmaf(dlam, wih[4*k+0], g[4*k+0]);
                v.y = x[4*k+1] - fmaf(dlam, wih[4*k+1], g[4*k+1]);
                v.z = x[4*k+2] - fmaf(dlam, wih[4*k+2], g[4*k+2]);
                v.w = x[4*k+3] - fmaf(dlam, wih[4*k+3], g[4*k+3]);
                o4[t + BLOCK * k] = v;
            }
            return;
        }

        // ---- Phase B: division-free fraction-to-boundary ----
        // dxn = -dx; min_k t_k = 1/max_k max(-dxn/(1-x), dxn/x)
        //   with 1/(1-x) = x*ti, 1/x = ti - x*ti. Store dxn into g[].
        float m = 0.0f;
        #pragma unroll
        for (int k = 0; k < PER; ++k) {
            const float dxn = fmaf(dlam, wih[k], g[k]);
            g[k] = dxn;
            const float ti  = tinv[k];
            const float xt  = x[k] * ti;                  // 1/(1-x)
            const float pt  = ti - xt;                    // 1/x
            m = fmaxf(m, fmaxf(-dxn * xt, dxn * pt));
        }
        m = block_reduce_max(m, ldsM[it & 1]);
        const float alpha = bcast_first(fminf(1.0f, 0.99f * raw_rcp(m)));

        #pragma unroll
        for (int k = 0; k < PER; ++k) x[k] = fmaf(-alpha, g[k], x[k]);
        lam = fmaf(alpha, dlam, lam);
        f2  = fmaf(-alpha, f2, f2);                       // F2 *= (1-alpha)
    }
}

extern "C" void kernel_launch(void* const* d_in, const int* in_sizes, int n_in,
                              void* d_out, int out_size, void* d_ws, size_t ws_size,
                              hipStream_t stream) {
    const float* costs   = (const float*)d_in[0];
    const float* weights = (const float*)d_in[1];
    float* out = (float*)d_out;
    const int B = in_sizes[0] / N_ELEM;   // 2048 rows
    ipm_knapsack_kernel<<<B, BLOCK, 0, stream>>>(costs, weights, out);
}

// Round 4
// 342.006 us; speedup vs baseline: 1.1042x; 1.1042x over previous
//
#include <hip/hip_runtime.h>

#define N_ELEM 4096
#define BLOCK 256
#define PER 16             // N_ELEM / BLOCK
#define NWAVE (BLOCK / 64)
#define NITER 40
#define CAPACITY 600.0f
#define DAMPING 1e-3f

// Raw v_rcp_f32 (~1 ulp); Newton path-following is self-correcting, tol 2e-2.
__device__ __forceinline__ float raw_rcp(float a) { return __builtin_amdgcn_rcpf(a); }

__device__ __forceinline__ float bcast_first(float v) {
    return __uint_as_float(__builtin_amdgcn_readfirstlane(__float_as_uint(v)));
}

// Fused 2-value block sum-reduction. ONE barrier; caller supplies parity
// buffer (2*NWAVE floats). Result broadcast to all threads.
__device__ __forceinline__ void block_reduce2(float& a, float& b, float* buf) {
    #pragma unroll
    for (int off = 32; off > 0; off >>= 1) {
        a += __shfl_xor(a, off, 64);
        b += __shfl_xor(b, off, 64);
    }
    const int wave = threadIdx.x >> 6;
    if ((threadIdx.x & 63) == 0) { buf[2 * wave] = a; buf[2 * wave + 1] = b; }
    __syncthreads();
    float a0 = 0.0f, b0 = 0.0f;
    #pragma unroll
    for (int i = 0; i < NWAVE; ++i) { a0 += buf[2 * i]; b0 += buf[2 * i + 1]; }
    a = a0; b = b0;
}

// Block max-reduction, ONE barrier, parity buffer (NWAVE floats), broadcast.
__device__ __forceinline__ float block_reduce_max(float v, float* buf) {
    #pragma unroll
    for (int off = 32; off > 0; off >>= 1) v = fmaxf(v, __shfl_xor(v, off, 64));
    const int wave = threadIdx.x >> 6;
    if ((threadIdx.x & 63) == 0) buf[wave] = v;
    __syncthreads();
    float m = buf[0];
    #pragma unroll
    for (int i = 1; i < NWAVE; ++i) m = fmaxf(m, buf[i]);
    return m;
}

// launch_bounds(256,2): unified reg budget 256/wave. All 6x16 state floats +
// temps (~110-130) stay in ARCH VGPRs -> zero v_accvgpr ping-pong. Evidence:
// R2 (84 arch regs) ~49 op-eq/elem/iter, R3 (48 arch regs) ~60, math needs
// ~27 -> AGPR moves were the gap. Occupancy cap 2 waves/SIMD is fine: kernel
// is VALU-issue-bound with 16x unrolled ILP per wave.
__global__ __launch_bounds__(BLOCK, 2) void ipm_knapsack_kernel(
        const float* __restrict__ costs,
        const float* __restrict__ weights,
        float* __restrict__ out) {
    // Parity-double-buffered reduction scratch: no tail barrier needed
    // (>=1 barrier separates a slot's readers from its next writer).
    __shared__ float ldsA[2][2 * NWAVE];
    __shared__ float ldsM[2][NWAVE];
    const int row = blockIdx.x;
    const int t   = threadIdx.x;

    float c[PER], w[PER], x[PER], g[PER], wih[PER], tinv[PER];

    const float4* c4 = reinterpret_cast<const float4*>(costs + (size_t)row * N_ELEM);
    const float4* w4 = reinterpret_cast<const float4*>(weights);
    #pragma unroll
    for (int k = 0; k < PER / 4; ++k) {
        float4 cc = c4[t + BLOCK * k];
        float4 ww = w4[t + BLOCK * k];
        c[4*k+0] = -cc.x; c[4*k+1] = -cc.y; c[4*k+2] = -cc.z; c[4*k+3] = -cc.w;
        w[4*k+0] =  ww.x; w[4*k+1] =  ww.y; w[4*k+2] =  ww.z; w[4*k+3] =  ww.w;
    }

    // x0 = capacity / sum(weights)
    float ws = 0.0f, zz = 0.0f;
    #pragma unroll
    for (int k = 0; k < PER; ++k) ws += w[k];
    block_reduce2(ws, zz, ldsA[0]);
    const float x0 = CAPACITY / ws;
    #pragma unroll
    for (int k = 0; k < PER; ++k) x[k] = x0;
    float lam = 0.0f;
    // Newton identity: sum(w*dx) = -F2  =>  F2 <- (1-alpha)*F2 analytically.
    float f2 = fmaf(x0, ws, -CAPACITY);

    for (int it = 0; it <= NITER; ++it) {
        const float mu   = (it < 10) ? __uint_as_float((unsigned)(127 - it) << 23) : DAMPING;
        const float m2mu = -2.0f * mu;

        // ---- Phase A: u=x(1-x); one rcp gives 1/u and 1/H = u^3*r ----
        float s1 = 0.0f, s2 = 0.0f;
        #pragma unroll
        for (int k = 0; k < PER; ++k) {
            const float xk = x[k], wk = w[k];
            const float p   = 1.0f - xk;
            const float u   = xk * p;
            const float d   = fmaf(m2mu, u, mu);          // mu*(1-2u) > 0
            const float r   = raw_rcp(u * d);
            const float ti  = r * d;                      // 1/u
            const float q   = xk - p;                     // 2x-1
            const float f1  = fmaf(mu * ti, q, fmaf(lam, wk, c[k]));
            const float u2  = u * u;
            const float iH  = (u2 * u) * r;               // 1/H
            const float gk  = f1 * iH;
            const float wi  = wk * iH;
            s1 = fmaf(wk, gk, s1);
            s2 = fmaf(wk, wi, s2);
            g[k] = gk; wih[k] = wi; tinv[k] = ti;
        }
        block_reduce2(s1, s2, ldsA[(it + 1) & 1]);
        const float dlam = bcast_first((f2 - s1) * raw_rcp(s2));

        if (it == NITER) {
            float4* o4 = reinterpret_cast<float4*>(out + (size_t)row * N_ELEM);
            #pragma unroll
            for (int k = 0; k < PER / 4; ++k) {
                float4 v;
                v.x = x[4*k+0] - fmaf(dlam, wih[4*k+0], g[4*k+0]);
                v.y = x[4*k+1] - fmaf(dlam, wih[4*k+1], g[4*k+1]);
                v.z = x[4*k+2] - fmaf(dlam, wih[4*k+2], g[4*k+2]);
                v.w = x[4*k+3] - fmaf(dlam, wih[4*k+3], g[4*k+3]);
                o4[t + BLOCK * k] = v;
            }
            return;
        }

        // ---- Phase B: division-free fraction-to-boundary ----
        // dxn = -dx; min_k t_k = 1/max_k max(-dxn/(1-x), dxn/x),
        // 1/(1-x) = x*ti, 1/x = ti - x*ti. Store dxn into g[].
        float m = 0.0f;
        #pragma unroll
        for (int k = 0; k < PER; ++k) {
            const float dxn = fmaf(dlam, wih[k], g[k]);
            g[k] = dxn;
            const float ti  = tinv[k];
            const float xt  = x[k] * ti;                  // 1/(1-x)
            const float pt  = ti - xt;                    // 1/x
            m = fmaxf(m, fmaxf(-dxn * xt, dxn * pt));
        }
        m = block_reduce_max(m, ldsM[it & 1]);
        const float alpha = bcast_first(fminf(1.0f, 0.99f * raw_rcp(m)));

        #pragma unroll
        for (int k = 0; k < PER; ++k) x[k] = fmaf(-alpha, g[k], x[k]);
        lam = fmaf(alpha, dlam, lam);
        f2  = fmaf(-alpha, f2, f2);                       // F2 *= (1-alpha)
    }
}

extern "C" void kernel_launch(void* const* d_in, const int* in_sizes, int n_in,
                              void* d_out, int out_size, void* d_ws, size_t ws_size,
                              hipStream_t stream) {
    const float* costs   = (const float*)d_in[0];
    const float* weights = (const float*)d_in[1];
    float* out = (float*)d_out;
    const int B = in_sizes[0] / N_ELEM;   // 2048 rows
    ipm_knapsack_kernel<<<B, BLOCK, 0, stream>>>(costs, weights, out);
}

// Round 5
// 300.148 us; speedup vs baseline: 1.2582x; 1.1395x over previous
//
#include <hip/hip_runtime.h>

#define N_ELEM 4096
#define BLOCK 256
#define PER 16             // N_ELEM / BLOCK
#define NWAVE (BLOCK / 64)
#define NITER 40
#define CAPACITY 600.0f
#define DAMPING 1e-3f

// Raw v_rcp_f32 (~1 ulp); Newton path-following is self-correcting, tol 2e-2.
__device__ __forceinline__ float raw_rcp(float a) { return __builtin_amdgcn_rcpf(a); }

__device__ __forceinline__ float bcast_first(float v) {
    return __uint_as_float(__builtin_amdgcn_readfirstlane(__float_as_uint(v)));
}

// Fused 2-value block sum-reduction. ONE barrier; caller supplies parity
// buffer (2*NWAVE floats). Result broadcast to all threads.
__device__ __forceinline__ void block_reduce2(float& a, float& b, float* buf) {
    #pragma unroll
    for (int off = 32; off > 0; off >>= 1) {
        a += __shfl_xor(a, off, 64);
        b += __shfl_xor(b, off, 64);
    }
    const int wave = threadIdx.x >> 6;
    if ((threadIdx.x & 63) == 0) { buf[2 * wave] = a; buf[2 * wave + 1] = b; }
    __syncthreads();
    float a0 = 0.0f, b0 = 0.0f;
    #pragma unroll
    for (int i = 0; i < NWAVE; ++i) { a0 += buf[2 * i]; b0 += buf[2 * i + 1]; }
    a = a0; b = b0;
}

// Block max-reduction, ONE barrier, parity buffer (NWAVE floats), broadcast.
__device__ __forceinline__ float block_reduce_max(float v, float* buf) {
    #pragma unroll
    for (int off = 32; off > 0; off >>= 1) v = fmaxf(v, __shfl_xor(v, off, 64));
    const int wave = threadIdx.x >> 6;
    if ((threadIdx.x & 63) == 0) buf[wave] = v;
    __syncthreads();
    float m = buf[0];
    #pragma unroll
    for (int i = 1; i < NWAVE; ++i) m = fmaxf(m, buf[i]);
    return m;
}

// Register-pressure design (R1-R4 lesson): the allocator consistently caps
// this kernel at ~88 ARCH VGPRs and silently AGPR-spills the rest, paying
// ~20 v_accvgpr moves/elem/iter (measured 49 op-eq vs 28 math). Fix: move
// the read-only c,w arrays (32 floats) to LDS scratch -- each thread reads
// back only its OWN elements via ds_read_b128 (immediate offsets, ~0 VALU
// cost, LDS pipe otherwise idle). Remaining reg state: x,g,wih,tinv = 64
// floats + temps ~ 78 < 88 => all-arch, no AGPR ping-pong.
__global__ __launch_bounds__(BLOCK, 3) void ipm_knapsack_kernel(
        const float* __restrict__ costs,
        const float* __restrict__ weights,
        float* __restrict__ out) {
    __shared__ float4 c4s[N_ELEM / 4];   // 16 KB: -costs (this row)
    __shared__ float4 w4s[N_ELEM / 4];   // 16 KB: weights
    // Parity-double-buffered reduction scratch (>=1 barrier between a slot's
    // readers and its next writer; verified pattern from R3/R4).
    __shared__ float ldsA[2][2 * NWAVE];
    __shared__ float ldsM[2][NWAVE];
    const int row = blockIdx.x;
    const int t   = threadIdx.x;

    float x[PER], g[PER], wih[PER], tinv[PER];

    // ---- Stage c (negated) and w into LDS; accumulate sum(w) on the fly ----
    const float4* cg = reinterpret_cast<const float4*>(costs + (size_t)row * N_ELEM);
    const float4* wg = reinterpret_cast<const float4*>(weights);
    float ws = 0.0f, zz = 0.0f;
    #pragma unroll
    for (int k = 0; k < PER / 4; ++k) {
        float4 cc = cg[t + BLOCK * k];
        float4 ww = wg[t + BLOCK * k];
        cc.x = -cc.x; cc.y = -cc.y; cc.z = -cc.z; cc.w = -cc.w;
        c4s[t + BLOCK * k] = cc;
        w4s[t + BLOCK * k] = ww;
        ws += (ww.x + ww.y) + (ww.z + ww.w);
    }
    block_reduce2(ws, zz, ldsA[0]);   // barrier also orders the LDS staging

    const float x0 = CAPACITY / ws;
    #pragma unroll
    for (int k = 0; k < PER; ++k) x[k] = x0;
    float lam = 0.0f;
    // Newton identity: sum(w*dx) = -F2  =>  F2 <- (1-alpha)*F2 analytically.
    float f2 = fmaf(x0, ws, -CAPACITY);

    for (int it = 0; it <= NITER; ++it) {
        const float mu   = (it < 10) ? __uint_as_float((unsigned)(127 - it) << 23) : DAMPING;
        const float m2mu = -2.0f * mu;

        // ---- Phase A: u=x(1-x); one rcp gives 1/u and 1/H = u^3*r ----
        float s1 = 0.0f, s2 = 0.0f;
        #pragma unroll
        for (int kk = 0; kk < PER / 4; ++kk) {
            const float4 cv = c4s[t + BLOCK * kk];
            const float4 wv = w4s[t + BLOCK * kk];
            const float ca[4] = {cv.x, cv.y, cv.z, cv.w};
            const float wa[4] = {wv.x, wv.y, wv.z, wv.w};
            #pragma unroll
            for (int j = 0; j < 4; ++j) {
                const int   k  = 4 * kk + j;
                const float xk = x[k], wk = wa[j];
                const float p   = 1.0f - xk;
                const float u   = xk * p;
                const float d   = fmaf(m2mu, u, mu);      // mu*(1-2u) > 0
                const float r   = raw_rcp(u * d);
                const float ti  = r * d;                  // 1/u
                const float q   = xk - p;                 // 2x-1
                const float f1  = fmaf(mu * ti, q, fmaf(lam, wk, ca[j]));
                const float u2  = u * u;
                const float iH  = (u2 * u) * r;           // 1/H
                const float gk  = f1 * iH;
                const float wi  = wk * iH;
                s1 = fmaf(wk, gk, s1);
                s2 = fmaf(wk, wi, s2);
                g[k] = gk; wih[k] = wi; tinv[k] = ti;
            }
        }
        block_reduce2(s1, s2, ldsA[(it + 1) & 1]);
        const float dlam = bcast_first((f2 - s1) * raw_rcp(s2));

        if (it == NITER) {
            float4* o4 = reinterpret_cast<float4*>(out + (size_t)row * N_ELEM);
            #pragma unroll
            for (int k = 0; k < PER / 4; ++k) {
                float4 v;
                v.x = x[4*k+0] - fmaf(dlam, wih[4*k+0], g[4*k+0]);
                v.y = x[4*k+1] - fmaf(dlam, wih[4*k+1], g[4*k+1]);
                v.z = x[4*k+2] - fmaf(dlam, wih[4*k+2], g[4*k+2]);
                v.w = x[4*k+3] - fmaf(dlam, wih[4*k+3], g[4*k+3]);
                o4[t + BLOCK * k] = v;
            }
            return;
        }

        // ---- Phase B: division-free fraction-to-boundary ----
        // dxn = -dx; min_k t_k = 1/max_k max(-dxn/(1-x), dxn/x),
        // 1/(1-x) = x*ti, 1/x = ti - x*ti. Store dxn into g[].
        float m = 0.0f;
        #pragma unroll
        for (int k = 0; k < PER; ++k) {
            const float dxn = fmaf(dlam, wih[k], g[k]);
            g[k] = dxn;
            const float ti  = tinv[k];
            const float xt  = x[k] * ti;                  // 1/(1-x)
            const float pt  = ti - xt;                    // 1/x
            m = fmaxf(m, fmaxf(-dxn * xt, dxn * pt));
        }
        m = block_reduce_max(m, ldsM[it & 1]);
        const float alpha = bcast_first(fminf(1.0f, 0.99f * raw_rcp(m)));

        #pragma unroll
        for (int k = 0; k < PER; ++k) x[k] = fmaf(-alpha, g[k], x[k]);
        lam = fmaf(alpha, dlam, lam);
        f2  = fmaf(-alpha, f2, f2);                       // F2 *= (1-alpha)
    }
}

extern "C" void kernel_launch(void* const* d_in, const int* in_sizes, int n_in,
                              void* d_out, int out_size, void* d_ws, size_t ws_size,
                              hipStream_t stream) {
    const float* costs   = (const float*)d_in[0];
    const float* weights = (const float*)d_in[1];
    float* out = (float*)d_out;
    const int B = in_sizes[0] / N_ELEM;   // 2048 rows
    ipm_knapsack_kernel<<<B, BLOCK, 0, stream>>>(costs, weights, out);
}